// Round 2
// baseline (1319.666 us; speedup 1.0000x reference)
//
#include <hip/hip_runtime.h>

typedef unsigned short u16;
typedef unsigned int   u32;
typedef __attribute__((ext_vector_type(8))) short short8;    // MFMA bf16 A/B frag
typedef __attribute__((ext_vector_type(8))) unsigned short u16x8;
typedef __attribute__((ext_vector_type(4))) float floatx4;

__device__ __forceinline__ float bf2f(u16 u) {
  union { u32 i; float f; } v; v.i = ((u32)u) << 16; return v.f;
}
__device__ __forceinline__ u16 f2bf(float f) {
  union { float f; u32 i; } v; v.f = f;
  u32 x = v.i;
  return (u16)((x + 0x7fffu + ((x >> 16) & 1u)) >> 16);  // RNE
}

// ---------------------------------------------------------------------------
// 0) convert the three weight matrices fp32 -> bf16 (row-major (N,K) kept).
__global__ __launch_bounds__(256) void k_cvtw(const float* __restrict__ qw,
    const float* __restrict__ kvw, const float* __restrict__ pw,
    u16* __restrict__ dst) {
  int i = blockIdx.x * 256 + threadIdx.x;          // 262144 total
  float v;
  if (i < 65536)        v = qw[i];
  else if (i < 196608)  v = kvw[i - 65536];
  else                  v = pw[i - 196608];
  dst[i] = f2bf(v);
}

// 1) bilinear 2x upsample of mask (8,1,64,64)->(8,1,128,128), half-pixel,
//    edge-clamped (== jax.image.resize at borders for 2x), times feat_mask.
__global__ __launch_bounds__(256) void k_interp(const float* __restrict__ mask,
                                                const float* __restrict__ fmask,
                                                float* __restrict__ E) {
  int idx = blockIdx.x * 256 + threadIdx.x;        // 131072
  int b = idx >> 14, y = (idx >> 7) & 127, x = idx & 127;
  int jy = y >> 1, jx = x >> 1;
  int y0, y1, x0, x1; float wy0, wx0;
  if (y & 1) { y0 = jy; y1 = jy + 1 > 63 ? 63 : jy + 1; wy0 = 0.75f; }
  else       { y0 = jy - 1 < 0 ? 0 : jy - 1; y1 = jy;    wy0 = 0.25f; }
  if (x & 1) { x0 = jx; x1 = jx + 1 > 63 ? 63 : jx + 1; wx0 = 0.75f; }
  else       { x0 = jx - 1 < 0 ? 0 : jx - 1; x1 = jx;    wx0 = 0.25f; }
  const float* mb = mask + (b << 12);
  float v0 = wx0 * mb[y0*64 + x0] + (1.f - wx0) * mb[y0*64 + x1];
  float v1 = wx0 * mb[y1*64 + x0] + (1.f - wx0) * mb[y1*64 + x1];
  float v  = wy0 * v0 + (1.f - wy0) * v1;
  E[idx] = v * fmask[y*128 + x];
}

// 2) per-window max of E >= 0.2 -> keep flag. one wave per window.
__global__ __launch_bounds__(64) void k_keep(const float* __restrict__ E,
                                             int* __restrict__ keepf) {
  int win = blockIdx.x;                       // 2048
  int lane = threadIdx.x;
  int b = win >> 8, wh = (win >> 4) & 15, ww = win & 15;
  int hi = lane >> 3, wi = lane & 7;
  float v = E[(b << 14) + (wh*8 + hi)*128 + ww*8 + wi];
  #pragma unroll
  for (int off = 32; off; off >>= 1) v = fmaxf(v, __shfl_xor(v, off, 64));
  if (lane == 0) keepf[win] = (v >= 0.2f) ? 1 : 0;
}

// 3) stage feat/pre_feat into (token, channel) row-major bf16 via LDS transpose.
//    Xw[t,c] = feat*fmask ; Tw[t,c] = pre*pmask*E.  block = one window.
__global__ __launch_bounds__(256) void k_stage(const float* __restrict__ feat,
    const float* __restrict__ fmask, const float* __restrict__ pre,
    const float* __restrict__ pmask, const float* __restrict__ E,
    u16* __restrict__ Xw, u16* __restrict__ Tw) {
  __shared__ u16 lds[64 * 257];                // [pix][c], +1 pad
  int win = blockIdx.x;
  int b = win >> 8, wh = (win >> 4) & 15, ww = win & 15;
  int h0 = wh * 8, w0 = ww * 8;
  int tid = threadIdx.x;
  int hi = tid & 7, cL = tid >> 3;             // cL in [0,32)
  int rowoff = (h0 + hi) * 128 + w0;
  float m[8];
  {
    floatx4 a = *(const floatx4*)(fmask + rowoff);
    floatx4 c = *(const floatx4*)(fmask + rowoff + 4);
    #pragma unroll
    for (int j = 0; j < 4; j++) { m[j] = a[j]; m[4 + j] = c[j]; }
  }
  // ---- X ----
  #pragma unroll
  for (int i = 0; i < 8; i++) {
    int c = i * 32 + cL;
    size_t g = (((size_t)(b*256 + c)) << 14) + rowoff;
    floatx4 f0 = *(const floatx4*)(feat + g);
    floatx4 f1 = *(const floatx4*)(feat + g + 4);
    #pragma unroll
    for (int j = 0; j < 4; j++) {
      lds[(hi*8 + j)*257 + c]     = f2bf(f0[j] * m[j]);
      lds[(hi*8 + j + 4)*257 + c] = f2bf(f1[j] * m[4 + j]);
    }
  }
  __syncthreads();
  #pragma unroll
  for (int i = 0; i < 32; i++) {
    int pix = i*2 + (tid >> 7);
    int c = (tid & 127) * 2;
    u32 u = (u32)lds[pix*257 + c] | ((u32)lds[pix*257 + c + 1] << 16);
    *(u32*)(Xw + (((size_t)(win*64 + pix)) << 8) + c) = u;
  }
  __syncthreads();
  // ---- T ----
  {
    floatx4 a = *(const floatx4*)(pmask + rowoff);
    floatx4 c = *(const floatx4*)(pmask + rowoff + 4);
    floatx4 e0 = *(const floatx4*)(E + (b << 14) + rowoff);
    floatx4 e1 = *(const floatx4*)(E + (b << 14) + rowoff + 4);
    #pragma unroll
    for (int j = 0; j < 4; j++) { m[j] = a[j] * e0[j]; m[4 + j] = c[j] * e1[j]; }
  }
  #pragma unroll
  for (int i = 0; i < 8; i++) {
    int c = i * 32 + cL;
    size_t g = (((size_t)(b*256 + c)) << 14) + rowoff;
    floatx4 f0 = *(const floatx4*)(pre + g);
    floatx4 f1 = *(const floatx4*)(pre + g + 4);
    #pragma unroll
    for (int j = 0; j < 4; j++) {
      lds[(hi*8 + j)*257 + c]     = f2bf(f0[j] * m[j]);
      lds[(hi*8 + j + 4)*257 + c] = f2bf(f1[j] * m[4 + j]);
    }
  }
  __syncthreads();
  #pragma unroll
  for (int i = 0; i < 32; i++) {
    int pix = i*2 + (tid >> 7);
    int c = (tid & 127) * 2;
    u32 u = (u32)lds[pix*257 + c] | ((u32)lds[pix*257 + c + 1] << 16);
    *(u32*)(Tw + (((size_t)(win*64 + pix)) << 8) + c) = u;
  }
}

// 4) C[M,N] = A[M,K] @ W[N,K]^T (+bias), bf16 in/out, fp32 accum.
//    wave tile 16x64, block tile 64x64.
__global__ __launch_bounds__(256) void k_gemm_bt(const u16* __restrict__ A,
    const u16* __restrict__ W, const float* __restrict__ bias,
    u16* __restrict__ C, int M, int N, int K) {
  int wave = threadIdx.x >> 6, lane = threadIdx.x & 63;
  int qq = lane >> 4, l = lane & 15;
  int row0 = blockIdx.x * 64 + wave * 16;
  int col0 = blockIdx.y * 64;
  floatx4 z = {0.f, 0.f, 0.f, 0.f};
  floatx4 acc[4] = {z, z, z, z};
  for (int kb = 0; kb < K; kb += 32) {
    short8 a = *(const short8*)(A + (size_t)(row0 + l) * K + kb + qq*8);
    #pragma unroll
    for (int t = 0; t < 4; t++) {
      short8 bf = *(const short8*)(W + (size_t)(col0 + t*16 + l) * K + kb + qq*8);
      acc[t] = __builtin_amdgcn_mfma_f32_16x16x32_bf16(a, bf, acc[t], 0, 0, 0);
    }
  }
  #pragma unroll
  for (int t = 0; t < 4; t++) {
    int col = col0 + t*16 + l;
    float bv = bias ? bias[col] : 0.f;
    #pragma unroll
    for (int r = 0; r < 4; r++) {
      int row = row0 + qq*4 + r;              // C/D map: col=lane&15, row=quad*4+reg
      C[(size_t)row * N + col] = f2bf(acc[t][r] + bv);
    }
  }
}

// 5) KV GEMM (N=512,K=256): K-half stored (t,c); V-half scattered transposed
//    into Vt[win][head][d][m] so attention B-frags are contiguous in m.
__global__ __launch_bounds__(256) void k_gemm_kv(const u16* __restrict__ A,
    const u16* __restrict__ W, u16* __restrict__ Kb, u16* __restrict__ Vt) {
  int wave = threadIdx.x >> 6, lane = threadIdx.x & 63;
  int qq = lane >> 4, l = lane & 15;
  int row0 = blockIdx.x * 64 + wave * 16;
  int col0 = blockIdx.y * 64;
  floatx4 z = {0.f, 0.f, 0.f, 0.f};
  floatx4 acc[4] = {z, z, z, z};
  for (int kb = 0; kb < 256; kb += 32) {
    short8 a = *(const short8*)(A + (size_t)(row0 + l) * 256 + kb + qq*8);
    #pragma unroll
    for (int t = 0; t < 4; t++) {
      short8 bf = *(const short8*)(W + (size_t)(col0 + t*16 + l) * 256 + kb + qq*8);
      acc[t] = __builtin_amdgcn_mfma_f32_16x16x32_bf16(a, bf, acc[t], 0, 0, 0);
    }
  }
  #pragma unroll
  for (int t = 0; t < 4; t++) {
    int col = col0 + t*16 + l;
    #pragma unroll
    for (int r = 0; r < 4; r++) {
      int row = row0 + qq*4 + r;
      u16 v = f2bf(acc[t][r]);
      if (col < 256) {
        Kb[(size_t)row * 256 + col] = v;
      } else {
        int cc = col - 256, hd = cc >> 6, d = cc & 63;
        int wn = row >> 6, mm = row & 63;
        Vt[((size_t)(wn*4 + hd)*64 + d)*64 + mm] = v;
      }
    }
  }
}

// 6) per-window cross attention. block = window (256 thr), wave = head.
__global__ __launch_bounds__(256) void k_attn(const u16* __restrict__ Q,
    const u16* __restrict__ Kb, const u16* __restrict__ Vt,
    u16* __restrict__ O) {
  __shared__ __align__(16) u16 P[4][64 * 72];
  int win = blockIdx.x;
  int head = threadIdx.x >> 6, lane = threadIdx.x & 63;
  int qq = lane >> 4, l = lane & 15;
  const u16* Qh = Q  + (size_t)win * 64 * 256 + head * 64;
  const u16* Kh = Kb + (size_t)win * 64 * 256 + head * 64;
  floatx4 z = {0.f, 0.f, 0.f, 0.f};
  floatx4 s[4][4];
  #pragma unroll
  for (int a = 0; a < 4; a++)
    #pragma unroll
    for (int b = 0; b < 4; b++) s[a][b] = z;
  #pragma unroll
  for (int kb = 0; kb < 64; kb += 32) {
    short8 af[4], bf[4];
    #pragma unroll
    for (int tn = 0; tn < 4; tn++)
      af[tn] = *(const short8*)(Qh + (size_t)(tn*16 + l) * 256 + kb + qq*8);
    #pragma unroll
    for (int tm = 0; tm < 4; tm++)
      bf[tm] = *(const short8*)(Kh + (size_t)(tm*16 + l) * 256 + kb + qq*8);
    #pragma unroll
    for (int tn = 0; tn < 4; tn++)
      #pragma unroll
      for (int tm = 0; tm < 4; tm++)
        s[tn][tm] = __builtin_amdgcn_mfma_f32_16x16x32_bf16(af[tn], bf[tm], s[tn][tm], 0, 0, 0);
  }
  // softmax over m (64 cols = 4 tm-tiles x 16 lanes of this quad)
  #pragma unroll
  for (int tn = 0; tn < 4; tn++) {
    #pragma unroll
    for (int r = 0; r < 4; r++) {
      float v[4];
      #pragma unroll
      for (int tm = 0; tm < 4; tm++) v[tm] = s[tn][tm][r] * 0.125f;  // hd^-0.5
      float mx = -3.0e38f;
      #pragma unroll
      for (int tm = 0; tm < 4; tm++) mx = fmaxf(mx, v[tm]);
      #pragma unroll
      for (int off = 1; off < 16; off <<= 1) mx = fmaxf(mx, __shfl_xor(mx, off, 64));
      float p0[4], sum = 0.f;
      #pragma unroll
      for (int tm = 0; tm < 4; tm++) { p0[tm] = __expf(v[tm] - mx); sum += p0[tm]; }
      #pragma unroll
      for (int off = 1; off < 16; off <<= 1) sum += __shfl_xor(sum, off, 64);
      float inv = 1.0f / sum;
      int n = tn*16 + qq*4 + r;
      #pragma unroll
      for (int tm = 0; tm < 4; tm++)
        P[head][n*72 + tm*16 + l] = f2bf(p0[tm] * inv);
    }
  }
  __syncthreads();
  floatx4 o[4][4];
  #pragma unroll
  for (int a = 0; a < 4; a++)
    #pragma unroll
    for (int b = 0; b < 4; b++) o[a][b] = z;
  #pragma unroll
  for (int kb = 0; kb < 64; kb += 32) {
    short8 af[4], bf[4];
    #pragma unroll
    for (int tn = 0; tn < 4; tn++)   // A-layout: row n=lane&15, k m=quad*8+j
      af[tn] = *(const short8*)(&P[head][(tn*16 + l)*72 + kb + qq*8]);
    #pragma unroll
    for (int td = 0; td < 4; td++)   // B from Vt[d][m], contiguous in m
      bf[td] = *(const short8*)(Vt + ((size_t)(win*4 + head)*64 + td*16 + l)*64 + kb + qq*8);
    #pragma unroll
    for (int tn = 0; tn < 4; tn++)
      #pragma unroll
      for (int td = 0; td < 4; td++)
        o[tn][td] = __builtin_amdgcn_mfma_f32_16x16x32_bf16(af[tn], bf[td], o[tn][td], 0, 0, 0);
  }
  #pragma unroll
  for (int tn = 0; tn < 4; tn++)
    #pragma unroll
    for (int td = 0; td < 4; td++)
      #pragma unroll
      for (int r = 0; r < 4; r++)
        O[(size_t)(win*64 + tn*16 + qq*4 + r) * 256 + head*64 + td*16 + l] =
            f2bf(o[tn][td][r]);
}

// 7) window_reverse + keep-zeroing + add masked feat -> xbuf (b,c,h,w) fp32.
__global__ __launch_bounds__(256) void k_reverse(const u16* __restrict__ heat,
    const int* __restrict__ keepf, const float* __restrict__ feat,
    const float* __restrict__ fmask, float* __restrict__ xbuf) {
  __shared__ u16 lds[64 * 257];
  int win = blockIdx.x;
  int b = win >> 8, wh = (win >> 4) & 15, ww = win & 15;
  int h0 = wh * 8, w0 = ww * 8;
  int tid = threadIdx.x;
  float kp = keepf[win] ? 1.f : 0.f;
  #pragma unroll
  for (int i = 0; i < 32; i++) {
    int pix = i*2 + (tid >> 7);
    int c = (tid & 127) * 2;
    u32 u = *(const u32*)(heat + (((size_t)(win*64 + pix)) << 8) + c);
    lds[pix*257 + c]     = (u16)(u & 0xffffu);
    lds[pix*257 + c + 1] = (u16)(u >> 16);
  }
  __syncthreads();
  int hi = tid & 7, cL = tid >> 3;
  int rowoff = (h0 + hi) * 128 + w0;
  float m[8];
  {
    floatx4 a = *(const floatx4*)(fmask + rowoff);
    floatx4 c = *(const floatx4*)(fmask + rowoff + 4);
    #pragma unroll
    for (int j = 0; j < 4; j++) { m[j] = a[j]; m[4 + j] = c[j]; }
  }
  #pragma unroll
  for (int i = 0; i < 8; i++) {
    int c = i * 32 + cL;
    size_t goff = (((size_t)(b*256 + c)) << 14) + rowoff;
    floatx4 f0 = *(const floatx4*)(feat + goff);
    floatx4 f1 = *(const floatx4*)(feat + goff + 4);
    floatx4 o0, o1;
    #pragma unroll
    for (int j = 0; j < 4; j++) {
      o0[j] = kp * bf2f(lds[(hi*8 + j)*257 + c])     + f0[j] * m[j];
      o1[j] = kp * bf2f(lds[(hi*8 + j + 4)*257 + c]) + f1[j] * m[4 + j];
    }
    *(floatx4*)(xbuf + goff)     = o0;
    *(floatx4*)(xbuf + goff + 4) = o1;
  }
}

// 8) BN stats: per (channel, batch) block reduces 16384 elems -> atomics.
__global__ __launch_bounds__(256) void k_stats(const float* __restrict__ xbuf,
                                               float* __restrict__ stats) {
  int c = blockIdx.x >> 3, b = blockIdx.x & 7;
  const float* p = xbuf + (((size_t)(b*256 + c)) << 14);
  float s = 0.f, ss = 0.f;
  #pragma unroll
  for (int i = 0; i < 16; i++) {
    floatx4 v4 = *(const floatx4*)(p + i*1024 + threadIdx.x*4);
    #pragma unroll
    for (int j = 0; j < 4; j++) { float v = v4[j]; s += v; ss += v*v; }
  }
  #pragma unroll
  for (int off = 1; off < 64; off <<= 1) {
    s  += __shfl_xor(s,  off, 64);
    ss += __shfl_xor(ss, off, 64);
  }
  __shared__ float rs[4], rss[4];
  int wave = threadIdx.x >> 6, lane = threadIdx.x & 63;
  if (lane == 0) { rs[wave] = s; rss[wave] = ss; }
  __syncthreads();
  if (threadIdx.x == 0) {
    atomicAdd(&stats[c],       rs[0] + rs[1] + rs[2] + rs[3]);
    atomicAdd(&stats[256 + c], rss[0] + rss[1] + rss[2] + rss[3]);
  }
}

// 9) fold mean/var/gamma/beta into per-channel scale+shift.
__global__ void k_scaleshift(const float* __restrict__ stats,
                             const float* __restrict__ gamma,
                             const float* __restrict__ beta,
                             float* __restrict__ scsh) {
  int c = threadIdx.x;
  const float invN = 1.0f / 131072.0f;
  float mean = stats[c] * invN;
  float var  = stats[256 + c] * invN - mean * mean;
  float sc = gamma[c] * rsqrtf(var + 1e-5f);
  scsh[c] = sc;
  scsh[256 + c] = beta[c] - mean * sc;
}

// 10) normalize in-place (xbuf == out, fp32).
__global__ __launch_bounds__(256) void k_norm(float* __restrict__ xbuf,
                                              const float* __restrict__ scsh) {
  size_t e = ((size_t)blockIdx.x * 256 + threadIdx.x) * 4;
  int c = (int)((e >> 14) & 255);
  float sc = scsh[c], sh = scsh[256 + c];
  floatx4 v4 = *(const floatx4*)(xbuf + e);
  #pragma unroll
  for (int j = 0; j < 4; j++) v4[j] = v4[j] * sc + sh;
  *(floatx4*)(xbuf + e) = v4;
}

extern "C" void kernel_launch(void* const* d_in, const int* in_sizes, int n_in,
                              void* d_out, int out_size, void* d_ws, size_t ws_size,
                              hipStream_t stream) {
  (void)in_sizes; (void)n_in; (void)out_size; (void)ws_size;
  const float* pre    = (const float*)d_in[0];
  const float* pmask  = (const float*)d_in[1];
  const float* feat   = (const float*)d_in[2];
  const float* fmask  = (const float*)d_in[3];
  const float* maskin = (const float*)d_in[4];
  const float* q_w    = (const float*)d_in[5];
  const float* kv_w   = (const float*)d_in[6];
  const float* proj_w = (const float*)d_in[7];
  const float* proj_b = (const float*)d_in[8];
  const float* gamma  = (const float*)d_in[9];
  const float* beta   = (const float*)d_in[10];
  float* out = (float*)d_out;

  const size_t NE = 33554432;                 // 131072 x 256
  u16* Xw = (u16*)d_ws;                       // staging X; later attention O
  u16* Tw = Xw + NE;                          // staging T; later heat
  u16* Qb = Tw + NE;                          // Q
  u16* Kb = Qb + NE;
  u16* Vt = Kb + NE;
  u16* Wb = Vt + NE;                          // bf16 weights: q(65536) kv(131072) proj(65536)
  float* E     = (float*)(Wb + 262144);       // 131072 floats
  int*   keepf = (int*)(E + 131072);          // 2048 ints
  float* stats = (float*)(keepf + 2048);      // sum[256], sumsq[256]
  float* scsh  = stats + 512;                 // scale[256], shift[256]

  hipMemsetAsync(stats, 0, 2048, stream);
  k_cvtw<<<1024, 256, 0, stream>>>(q_w, kv_w, proj_w, Wb);
  k_interp<<<512, 256, 0, stream>>>(maskin, fmask, E);
  k_keep<<<2048, 64, 0, stream>>>(E, keepf);
  k_stage<<<2048, 256, 0, stream>>>(feat, fmask, pre, pmask, E, Xw, Tw);
  k_gemm_bt<<<dim3(2048, 4), 256, 0, stream>>>(Xw, Wb, nullptr, Qb, 131072, 256, 256);
  k_gemm_kv<<<dim3(2048, 8), 256, 0, stream>>>(Tw, Wb + 65536, Kb, Vt);
  k_attn<<<2048, 256, 0, stream>>>(Qb, Kb, Vt, Xw /*O (Xw dead)*/);
  k_gemm_bt<<<dim3(2048, 4), 256, 0, stream>>>(Xw /*O*/, Wb + 196608, proj_b,
                                               Tw /*heat (Tw dead)*/, 131072, 256, 256);
  k_reverse<<<2048, 256, 0, stream>>>(Tw /*heat*/, keepf, feat, fmask, out /*xbuf fp32*/);
  k_stats<<<2048, 256, 0, stream>>>(out, stats);
  k_scaleshift<<<1, 256, 0, stream>>>(stats, gamma, beta, scsh);
  k_norm<<<32768, 256, 0, stream>>>(out, scsh);
}

// Round 3
// 923.224 us; speedup vs baseline: 1.4294x; 1.4294x over previous
//
#include <hip/hip_runtime.h>

typedef unsigned short u16;
typedef unsigned int   u32;
typedef __attribute__((ext_vector_type(8))) short short8;    // MFMA bf16 A/B frag
typedef __attribute__((ext_vector_type(8))) unsigned short u16x8;
typedef __attribute__((ext_vector_type(4))) float floatx4;

__device__ __forceinline__ float bf2f(u16 u) {
  union { u32 i; float f; } v; v.i = ((u32)u) << 16; return v.f;
}
__device__ __forceinline__ u16 f2bf(float f) {
  union { float f; u32 i; } v; v.f = f;
  u32 x = v.i;
  return (u16)((x + 0x7fffu + ((x >> 16) & 1u)) >> 16);  // RNE
}

// async global->LDS, 16B per lane. LDS dest = wave-uniform base + lane*16B.
__device__ __forceinline__ void gl_lds16(const u16* g, u16* l) {
  __builtin_amdgcn_global_load_lds(
      (const __attribute__((address_space(1))) void*)g,
      (__attribute__((address_space(3))) void*)l, 16, 0, 0);
}

// ---------------------------------------------------------------------------
// 0) convert the three weight matrices fp32 -> bf16 (row-major (N,K) kept).
__global__ __launch_bounds__(256) void k_cvtw(const float* __restrict__ qw,
    const float* __restrict__ kvw, const float* __restrict__ pw,
    u16* __restrict__ dst) {
  int i = blockIdx.x * 256 + threadIdx.x;          // 262144 total
  float v;
  if (i < 65536)        v = qw[i];
  else if (i < 196608)  v = kvw[i - 65536];
  else                  v = pw[i - 196608];
  dst[i] = f2bf(v);
}

// 1) bilinear 2x upsample of mask (8,1,64,64)->(8,1,128,128), half-pixel,
//    edge-clamped, times feat_mask.
__global__ __launch_bounds__(256) void k_interp(const float* __restrict__ mask,
                                                const float* __restrict__ fmask,
                                                float* __restrict__ E) {
  int idx = blockIdx.x * 256 + threadIdx.x;        // 131072
  int b = idx >> 14, y = (idx >> 7) & 127, x = idx & 127;
  int jy = y >> 1, jx = x >> 1;
  int y0, y1, x0, x1; float wy0, wx0;
  if (y & 1) { y0 = jy; y1 = jy + 1 > 63 ? 63 : jy + 1; wy0 = 0.75f; }
  else       { y0 = jy - 1 < 0 ? 0 : jy - 1; y1 = jy;    wy0 = 0.25f; }
  if (x & 1) { x0 = jx; x1 = jx + 1 > 63 ? 63 : jx + 1; wx0 = 0.75f; }
  else       { x0 = jx - 1 < 0 ? 0 : jx - 1; x1 = jx;    wx0 = 0.25f; }
  const float* mb = mask + (b << 12);
  float v0 = wx0 * mb[y0*64 + x0] + (1.f - wx0) * mb[y0*64 + x1];
  float v1 = wx0 * mb[y1*64 + x0] + (1.f - wx0) * mb[y1*64 + x1];
  float v  = wy0 * v0 + (1.f - wy0) * v1;
  E[idx] = v * fmask[y*128 + x];
}

// 2) per-window max of E >= 0.2 -> keep flag.
__global__ __launch_bounds__(64) void k_keep(const float* __restrict__ E,
                                             int* __restrict__ keepf) {
  int win = blockIdx.x;                       // 2048
  int lane = threadIdx.x;
  int b = win >> 8, wh = (win >> 4) & 15, ww = win & 15;
  int hi = lane >> 3, wi = lane & 7;
  float v = E[(b << 14) + (wh*8 + hi)*128 + ww*8 + wi];
  #pragma unroll
  for (int off = 32; off; off >>= 1) v = fmaxf(v, __shfl_xor(v, off, 64));
  if (lane == 0) keepf[win] = (v >= 0.2f) ? 1 : 0;
}

// 3) stage feat/pre_feat into (token, channel) row-major bf16 via LDS transpose.
__global__ __launch_bounds__(256) void k_stage(const float* __restrict__ feat,
    const float* __restrict__ fmask, const float* __restrict__ pre,
    const float* __restrict__ pmask, const float* __restrict__ E,
    u16* __restrict__ Xw, u16* __restrict__ Tw) {
  __shared__ u16 lds[64 * 257];                // [pix][c], +1 pad
  int win = blockIdx.x;
  int b = win >> 8, wh = (win >> 4) & 15, ww = win & 15;
  int h0 = wh * 8, w0 = ww * 8;
  int tid = threadIdx.x;
  int hi = tid & 7, cL = tid >> 3;             // cL in [0,32)
  int rowoff = (h0 + hi) * 128 + w0;
  float m[8];
  {
    floatx4 a = *(const floatx4*)(fmask + rowoff);
    floatx4 c = *(const floatx4*)(fmask + rowoff + 4);
    #pragma unroll
    for (int j = 0; j < 4; j++) { m[j] = a[j]; m[4 + j] = c[j]; }
  }
  #pragma unroll
  for (int i = 0; i < 8; i++) {
    int c = i * 32 + cL;
    size_t g = (((size_t)(b*256 + c)) << 14) + rowoff;
    floatx4 f0 = *(const floatx4*)(feat + g);
    floatx4 f1 = *(const floatx4*)(feat + g + 4);
    #pragma unroll
    for (int j = 0; j < 4; j++) {
      lds[(hi*8 + j)*257 + c]     = f2bf(f0[j] * m[j]);
      lds[(hi*8 + j + 4)*257 + c] = f2bf(f1[j] * m[4 + j]);
    }
  }
  __syncthreads();
  #pragma unroll
  for (int i = 0; i < 32; i++) {
    int pix = i*2 + (tid >> 7);
    int c = (tid & 127) * 2;
    u32 u = (u32)lds[pix*257 + c] | ((u32)lds[pix*257 + c + 1] << 16);
    *(u32*)(Xw + (((size_t)(win*64 + pix)) << 8) + c) = u;
  }
  __syncthreads();
  {
    floatx4 a = *(const floatx4*)(pmask + rowoff);
    floatx4 c = *(const floatx4*)(pmask + rowoff + 4);
    floatx4 e0 = *(const floatx4*)(E + (b << 14) + rowoff);
    floatx4 e1 = *(const floatx4*)(E + (b << 14) + rowoff + 4);
    #pragma unroll
    for (int j = 0; j < 4; j++) { m[j] = a[j] * e0[j]; m[4 + j] = c[j] * e1[j]; }
  }
  #pragma unroll
  for (int i = 0; i < 8; i++) {
    int c = i * 32 + cL;
    size_t g = (((size_t)(b*256 + c)) << 14) + rowoff;
    floatx4 f0 = *(const floatx4*)(pre + g);
    floatx4 f1 = *(const floatx4*)(pre + g + 4);
    #pragma unroll
    for (int j = 0; j < 4; j++) {
      lds[(hi*8 + j)*257 + c]     = f2bf(f0[j] * m[j]);
      lds[(hi*8 + j + 4)*257 + c] = f2bf(f1[j] * m[4 + j]);
    }
  }
  __syncthreads();
  #pragma unroll
  for (int i = 0; i < 32; i++) {
    int pix = i*2 + (tid >> 7);
    int c = (tid & 127) * 2;
    u32 u = (u32)lds[pix*257 + c] | ((u32)lds[pix*257 + c + 1] << 16);
    *(u32*)(Tw + (((size_t)(win*64 + pix)) << 8) + c) = u;
  }
}

// ---------------------------------------------------------------------------
// m97-style 128x128 GEMM: C[M,256] = A[M,256] @ W[256,256]^T (+bias).
// BK=32, global_load_lds(16B) staging, 4 waves x 64x64 quadrants.
// XCD swizzle: blocks sharing an A-tile run consecutively on the same XCD.
__global__ __launch_bounds__(256) void k_gemm128n(const u16* __restrict__ A,
    const u16* __restrict__ W, const float* __restrict__ bias,
    u16* __restrict__ C) {
  __shared__ u16 As[128 * 32], Ws[128 * 32];   // 8 KB each
  int bi = blockIdx.x;                          // 2048
  int xcd = bi & 7, t = bi >> 3;
  int y = t & 1, xg = t >> 1;                   // Ny = 2
  int row0 = (xg * 8 + xcd) << 7, col0 = y << 7;
  int wv = threadIdx.x >> 6, lane = threadIdx.x & 63;
  int qq = lane >> 4, l = lane & 15;
  int srow = lane >> 2, skoff = (lane & 3) << 3;
  const u16* Ag = A + (size_t)(row0 + wv*32 + srow) * 256 + skoff;
  const u16* Wg = W + (size_t)(col0 + wv*32 + srow) * 256 + skoff;
  u16* AsW = As + (wv*32) * 32;
  u16* WsW = Ws + (wv*32) * 32;
  int wr = wv >> 1, wc = wv & 1;
  int r0 = wr * 64, c0 = wc * 64;
  floatx4 z = {0.f, 0.f, 0.f, 0.f};
  floatx4 acc[4][4];
  #pragma unroll
  for (int a = 0; a < 4; a++)
    #pragma unroll
    for (int b = 0; b < 4; b++) acc[a][b] = z;
  for (int kb = 0; kb < 256; kb += 32) {
    __syncthreads();
    gl_lds16(Ag + kb,            AsW);
    gl_lds16(Ag + kb + 16*256,   AsW + 16*32);
    gl_lds16(Wg + kb,            WsW);
    gl_lds16(Wg + kb + 16*256,   WsW + 16*32);
    __syncthreads();
    short8 af[4], wf[4];
    #pragma unroll
    for (int tn = 0; tn < 4; tn++)
      af[tn] = *(const short8*)&As[(r0 + tn*16 + l)*32 + qq*8];
    #pragma unroll
    for (int tm = 0; tm < 4; tm++)
      wf[tm] = *(const short8*)&Ws[(c0 + tm*16 + l)*32 + qq*8];
    #pragma unroll
    for (int tn = 0; tn < 4; tn++)
      #pragma unroll
      for (int tm = 0; tm < 4; tm++)
        acc[tn][tm] = __builtin_amdgcn_mfma_f32_16x16x32_bf16(af[tn], wf[tm], acc[tn][tm], 0, 0, 0);
  }
  #pragma unroll
  for (int tm = 0; tm < 4; tm++) {
    int col = col0 + c0 + tm*16 + l;
    float bv = bias ? bias[col] : 0.f;
    #pragma unroll
    for (int tn = 0; tn < 4; tn++) {
      #pragma unroll
      for (int r = 0; r < 4; r++) {
        int row = row0 + r0 + tn*16 + qq*4 + r;   // C/D map: col=lane&15, row=quad*4+reg
        C[(size_t)row * 256 + col] = f2bf(acc[tn][tm][r] + bv);
      }
    }
  }
}

// KV variant: N=512 (Ny=4). cols<256 -> Kb[(t,c)]; cols>=256 -> V scattered
// transposed into Vt[win][head][d][m].
__global__ __launch_bounds__(256) void k_gemm128kv(const u16* __restrict__ A,
    const u16* __restrict__ W, u16* __restrict__ Kb, u16* __restrict__ Vt) {
  __shared__ u16 As[128 * 32], Ws[128 * 32];
  int bi = blockIdx.x;                          // 4096
  int xcd = bi & 7, t = bi >> 3;
  int y = t & 3, xg = t >> 2;                   // Ny = 4
  int row0 = (xg * 8 + xcd) << 7, col0 = y << 7;
  int wv = threadIdx.x >> 6, lane = threadIdx.x & 63;
  int qq = lane >> 4, l = lane & 15;
  int srow = lane >> 2, skoff = (lane & 3) << 3;
  const u16* Ag = A + (size_t)(row0 + wv*32 + srow) * 256 + skoff;
  const u16* Wg = W + (size_t)(col0 + wv*32 + srow) * 256 + skoff;
  u16* AsW = As + (wv*32) * 32;
  u16* WsW = Ws + (wv*32) * 32;
  int wr = wv >> 1, wc = wv & 1;
  int r0 = wr * 64, c0 = wc * 64;
  floatx4 z = {0.f, 0.f, 0.f, 0.f};
  floatx4 acc[4][4];
  #pragma unroll
  for (int a = 0; a < 4; a++)
    #pragma unroll
    for (int b = 0; b < 4; b++) acc[a][b] = z;
  for (int kb = 0; kb < 256; kb += 32) {
    __syncthreads();
    gl_lds16(Ag + kb,            AsW);
    gl_lds16(Ag + kb + 16*256,   AsW + 16*32);
    gl_lds16(Wg + kb,            WsW);
    gl_lds16(Wg + kb + 16*256,   WsW + 16*32);
    __syncthreads();
    short8 af[4], wf[4];
    #pragma unroll
    for (int tn = 0; tn < 4; tn++)
      af[tn] = *(const short8*)&As[(r0 + tn*16 + l)*32 + qq*8];
    #pragma unroll
    for (int tm = 0; tm < 4; tm++)
      wf[tm] = *(const short8*)&Ws[(c0 + tm*16 + l)*32 + qq*8];
    #pragma unroll
    for (int tn = 0; tn < 4; tn++)
      #pragma unroll
      for (int tm = 0; tm < 4; tm++)
        acc[tn][tm] = __builtin_amdgcn_mfma_f32_16x16x32_bf16(af[tn], wf[tm], acc[tn][tm], 0, 0, 0);
  }
  #pragma unroll
  for (int tm = 0; tm < 4; tm++) {
    int col = col0 + c0 + tm*16 + l;
    #pragma unroll
    for (int tn = 0; tn < 4; tn++) {
      #pragma unroll
      for (int r = 0; r < 4; r++) {
        int row = row0 + r0 + tn*16 + qq*4 + r;
        u16 v = f2bf(acc[tn][tm][r]);
        if (col < 256) {
          Kb[(size_t)row * 256 + col] = v;
        } else {
          int cc = col - 256, hd = cc >> 6, d = cc & 63;
          int wn = row >> 6, mm = row & 63;
          Vt[((size_t)(wn*4 + hd)*64 + d)*64 + mm] = v;
        }
      }
    }
  }
}

// 6) per-window cross attention. block = window (256 thr), wave = head.
__global__ __launch_bounds__(256) void k_attn(const u16* __restrict__ Q,
    const u16* __restrict__ Kb, const u16* __restrict__ Vt,
    u16* __restrict__ O) {
  __shared__ __align__(16) u16 P[4][64 * 72];
  int win = blockIdx.x;
  int head = threadIdx.x >> 6, lane = threadIdx.x & 63;
  int qq = lane >> 4, l = lane & 15;
  const u16* Qh = Q  + (size_t)win * 64 * 256 + head * 64;
  const u16* Kh = Kb + (size_t)win * 64 * 256 + head * 64;
  floatx4 z = {0.f, 0.f, 0.f, 0.f};
  floatx4 s[4][4];
  #pragma unroll
  for (int a = 0; a < 4; a++)
    #pragma unroll
    for (int b = 0; b < 4; b++) s[a][b] = z;
  #pragma unroll
  for (int kb = 0; kb < 64; kb += 32) {
    short8 af[4], bf[4];
    #pragma unroll
    for (int tn = 0; tn < 4; tn++)
      af[tn] = *(const short8*)(Qh + (size_t)(tn*16 + l) * 256 + kb + qq*8);
    #pragma unroll
    for (int tm = 0; tm < 4; tm++)
      bf[tm] = *(const short8*)(Kh + (size_t)(tm*16 + l) * 256 + kb + qq*8);
    #pragma unroll
    for (int tn = 0; tn < 4; tn++)
      #pragma unroll
      for (int tm = 0; tm < 4; tm++)
        s[tn][tm] = __builtin_amdgcn_mfma_f32_16x16x32_bf16(af[tn], bf[tm], s[tn][tm], 0, 0, 0);
  }
  #pragma unroll
  for (int tn = 0; tn < 4; tn++) {
    #pragma unroll
    for (int r = 0; r < 4; r++) {
      float v[4];
      #pragma unroll
      for (int tm = 0; tm < 4; tm++) v[tm] = s[tn][tm][r] * 0.125f;  // hd^-0.5
      float mx = -3.0e38f;
      #pragma unroll
      for (int tm = 0; tm < 4; tm++) mx = fmaxf(mx, v[tm]);
      #pragma unroll
      for (int off = 1; off < 16; off <<= 1) mx = fmaxf(mx, __shfl_xor(mx, off, 64));
      float p0[4], sum = 0.f;
      #pragma unroll
      for (int tm = 0; tm < 4; tm++) { p0[tm] = __expf(v[tm] - mx); sum += p0[tm]; }
      #pragma unroll
      for (int off = 1; off < 16; off <<= 1) sum += __shfl_xor(sum, off, 64);
      float inv = 1.0f / sum;
      int n = tn*16 + qq*4 + r;
      #pragma unroll
      for (int tm = 0; tm < 4; tm++)
        P[head][n*72 + tm*16 + l] = f2bf(p0[tm] * inv);
    }
  }
  __syncthreads();
  floatx4 o[4][4];
  #pragma unroll
  for (int a = 0; a < 4; a++)
    #pragma unroll
    for (int b = 0; b < 4; b++) o[a][b] = z;
  #pragma unroll
  for (int kb = 0; kb < 64; kb += 32) {
    short8 af[4], bf[4];
    #pragma unroll
    for (int tn = 0; tn < 4; tn++)   // A-layout: row n=lane&15, k m=quad*8+j
      af[tn] = *(const short8*)(&P[head][(tn*16 + l)*72 + kb + qq*8]);
    #pragma unroll
    for (int td = 0; td < 4; td++)   // B from Vt[d][m], contiguous in m
      bf[td] = *(const short8*)(Vt + ((size_t)(win*4 + head)*64 + td*16 + l)*64 + kb + qq*8);
    #pragma unroll
    for (int tn = 0; tn < 4; tn++)
      #pragma unroll
      for (int td = 0; td < 4; td++)
        o[tn][td] = __builtin_amdgcn_mfma_f32_16x16x32_bf16(af[tn], bf[td], o[tn][td], 0, 0, 0);
  }
  #pragma unroll
  for (int tn = 0; tn < 4; tn++)
    #pragma unroll
    for (int td = 0; td < 4; td++)
      #pragma unroll
      for (int r = 0; r < 4; r++)
        O[(size_t)(win*64 + tn*16 + qq*4 + r) * 256 + head*64 + td*16 + l] =
            f2bf(o[tn][td][r]);
}

// 7) window_reverse + keep-zeroing + residual add -> xbuf fp32, fused BN stats.
__global__ __launch_bounds__(256) void k_reverse(const u16* __restrict__ heat,
    const int* __restrict__ keepf, const float* __restrict__ feat,
    const float* __restrict__ fmask, float* __restrict__ xbuf,
    float* __restrict__ stats) {
  __shared__ u16 lds[64 * 257];
  int win = blockIdx.x;
  int b = win >> 8, wh = (win >> 4) & 15, ww = win & 15;
  int h0 = wh * 8, w0 = ww * 8;
  int tid = threadIdx.x;
  float kp = keepf[win] ? 1.f : 0.f;
  #pragma unroll
  for (int i = 0; i < 32; i++) {
    int pix = i*2 + (tid >> 7);
    int c = (tid & 127) * 2;
    u32 u = *(const u32*)(heat + (((size_t)(win*64 + pix)) << 8) + c);
    lds[pix*257 + c]     = (u16)(u & 0xffffu);
    lds[pix*257 + c + 1] = (u16)(u >> 16);
  }
  __syncthreads();
  int hi = tid & 7, cL = tid >> 3;
  int rowoff = (h0 + hi) * 128 + w0;
  float m[8];
  {
    floatx4 a = *(const floatx4*)(fmask + rowoff);
    floatx4 c = *(const floatx4*)(fmask + rowoff + 4);
    #pragma unroll
    for (int j = 0; j < 4; j++) { m[j] = a[j]; m[4 + j] = c[j]; }
  }
  #pragma unroll
  for (int i = 0; i < 8; i++) {
    int c = i * 32 + cL;
    size_t goff = (((size_t)(b*256 + c)) << 14) + rowoff;
    floatx4 f0 = *(const floatx4*)(feat + goff);
    floatx4 f1 = *(const floatx4*)(feat + goff + 4);
    floatx4 o0, o1;
    float ls = 0.f, lss = 0.f;
    #pragma unroll
    for (int j = 0; j < 4; j++) {
      o0[j] = kp * bf2f(lds[(hi*8 + j)*257 + c])     + f0[j] * m[j];
      o1[j] = kp * bf2f(lds[(hi*8 + j + 4)*257 + c]) + f1[j] * m[4 + j];
      ls += o0[j] + o1[j];
      lss += o0[j]*o0[j] + o1[j]*o1[j];
    }
    *(floatx4*)(xbuf + goff)     = o0;
    *(floatx4*)(xbuf + goff + 4) = o1;
    // reduce the 8 pixels-rows (hi) of this channel: lanes differ in bits 0..2
    #pragma unroll
    for (int off = 1; off < 8; off <<= 1) {
      ls  += __shfl_xor(ls,  off, 64);
      lss += __shfl_xor(lss, off, 64);
    }
    if (hi == 0) {
      atomicAdd(&stats[c],       ls);
      atomicAdd(&stats[256 + c], lss);
    }
  }
}

// 9) fold mean/var/gamma/beta into per-channel scale+shift.
__global__ void k_scaleshift(const float* __restrict__ stats,
                             const float* __restrict__ gamma,
                             const float* __restrict__ beta,
                             float* __restrict__ scsh) {
  int c = threadIdx.x;
  const float invN = 1.0f / 131072.0f;
  float mean = stats[c] * invN;
  float var  = stats[256 + c] * invN - mean * mean;
  float sc = gamma[c] * rsqrtf(var + 1e-5f);
  scsh[c] = sc;
  scsh[256 + c] = beta[c] - mean * sc;
}

// 10) normalize in-place (xbuf == out, fp32).
__global__ __launch_bounds__(256) void k_norm(float* __restrict__ xbuf,
                                              const float* __restrict__ scsh) {
  size_t e = ((size_t)blockIdx.x * 256 + threadIdx.x) * 4;
  int c = (int)((e >> 14) & 255);
  float sc = scsh[c], sh = scsh[256 + c];
  floatx4 v4 = *(const floatx4*)(xbuf + e);
  #pragma unroll
  for (int j = 0; j < 4; j++) v4[j] = v4[j] * sc + sh;
  *(floatx4*)(xbuf + e) = v4;
}

extern "C" void kernel_launch(void* const* d_in, const int* in_sizes, int n_in,
                              void* d_out, int out_size, void* d_ws, size_t ws_size,
                              hipStream_t stream) {
  (void)in_sizes; (void)n_in; (void)out_size; (void)ws_size;
  const float* pre    = (const float*)d_in[0];
  const float* pmask  = (const float*)d_in[1];
  const float* feat   = (const float*)d_in[2];
  const float* fmask  = (const float*)d_in[3];
  const float* maskin = (const float*)d_in[4];
  const float* q_w    = (const float*)d_in[5];
  const float* kv_w   = (const float*)d_in[6];
  const float* proj_w = (const float*)d_in[7];
  const float* proj_b = (const float*)d_in[8];
  const float* gamma  = (const float*)d_in[9];
  const float* beta   = (const float*)d_in[10];
  float* out = (float*)d_out;

  const size_t NE = 33554432;                 // 131072 x 256
  u16* Xw = (u16*)d_ws;                       // staging X; later attention O
  u16* Tw = Xw + NE;                          // staging T; later heat
  u16* Qb = Tw + NE;                          // Q
  u16* Kb = Qb + NE;
  u16* Vt = Kb + NE;
  u16* Wb = Vt + NE;                          // bf16 weights: q(65536) kv(131072) proj(65536)
  float* E     = (float*)(Wb + 262144);       // 131072 floats
  int*   keepf = (int*)(E + 131072);          // 2048 ints
  float* stats = (float*)(keepf + 2048);      // sum[256], sumsq[256]
  float* scsh  = stats + 512;                 // scale[256], shift[256]

  hipMemsetAsync(stats, 0, 2048, stream);
  k_cvtw<<<1024, 256, 0, stream>>>(q_w, kv_w, proj_w, Wb);
  k_interp<<<512, 256, 0, stream>>>(maskin, fmask, E);
  k_keep<<<2048, 64, 0, stream>>>(E, keepf);
  k_stage<<<2048, 256, 0, stream>>>(feat, fmask, pre, pmask, E, Xw, Tw);
  k_gemm128n<<<2048, 256, 0, stream>>>(Xw, Wb, nullptr, Qb);
  k_gemm128kv<<<4096, 256, 0, stream>>>(Tw, Wb + 65536, Kb, Vt);
  k_attn<<<2048, 256, 0, stream>>>(Qb, Kb, Vt, Xw /*O (Xw dead)*/);
  k_gemm128n<<<2048, 256, 0, stream>>>(Xw /*O*/, Wb + 196608, proj_b, Tw /*heat*/);
  k_reverse<<<2048, 256, 0, stream>>>(Tw /*heat*/, keepf, feat, fmask,
                                      out /*xbuf fp32*/, stats);
  k_scaleshift<<<1, 256, 0, stream>>>(stats, gamma, beta, scsh);
  k_norm<<<32768, 256, 0, stream>>>(out, scsh);
}